// Round 9
// baseline (2077.716 us; speedup 1.0000x reference)
//
#include <hip/hip_runtime.h>
#include <cstdint>

#define NROW 6144
#define HDIM 512
#define DOUT 256
#define NEG_INF (-__builtin_inff())

typedef _Float16 half8 __attribute__((ext_vector_type(8)));
typedef _Float16 half4v __attribute__((ext_vector_type(4)));
typedef float f32x4 __attribute__((ext_vector_type(4)));

#define BARRIER() asm volatile("s_barrier" ::: "memory")
#define LGKM0()   asm volatile("s_waitcnt lgkmcnt(0)" ::: "memory")
#define VMCNT4()  asm volatile("s_waitcnt vmcnt(4)" ::: "memory")
#define VMCNT0()  asm volatile("s_waitcnt vmcnt(0)" ::: "memory")

__device__ __forceinline__ void gld_lds16(void* lds, const void* g) {
  __builtin_amdgcn_global_load_lds(
      (const __attribute__((address_space(1))) void*)g,
      (__attribute__((address_space(3))) void*)lds, 16, 0, 0);
}

// ============== gemm256: 8-phase 256x256 GEMM (proven r5-r7 schedule) ==============
// C[M,N] = A[M,K]*B[N,K]^T (row-major, f16 in, f32 acc, f16 out). Stage ledger:
// ph1 A(1,h0,T+1) ph2 A(1,h1,T+1) ph3 B(0,h0,T+2) ph4 B(0,h1,T+2)
// ph5 A(0,h0,T+2) ph6 A(0,h1,T+2) ph7 B(1,h0,T+3) ph8 B(1,h1,T+3); vmcnt(4) at
// ph4/ph8; tail vmcnt(0). LDS swizzle: 16B slot s of row r holds logical s^(r&7).
__global__ __launch_bounds__(512, 2)
void gemm256(const _Float16* __restrict__ A, int lda,
             const _Float16* __restrict__ B, int ldb,
             _Float16* __restrict__ C, int ldc, int Kc, long MN)
{
  __shared__ _Float16 As[2][256][64];
  __shared__ _Float16 Bs[2][256][64];
  const int tid = threadIdx.x;
  const int wave = tid >> 6, lane = tid & 63;
  const int wr = wave >> 2, wc = wave & 3;

  const int gx = gridDim.x, gy = gridDim.y;
  const int nwg = gx * gy * gridDim.z;
  int lin = (blockIdx.z * gy + blockIdx.y) * gx + blockIdx.x;
  int swz = (nwg % 8 == 0) ? ((lin % 8) * (nwg >> 3) + (lin >> 3)) : lin;
  const int bx = swz % gx, by = (swz / gx) % gy, bz = swz / (gx * gy);
  const int row0 = bx * 256, col0 = by * 256;
  const _Float16* Ab = A + (size_t)row0 * lda + (size_t)bz * Kc;
  const _Float16* Bb = B + (size_t)col0 * ldb + (size_t)bz * Kc;
  const int nt = Kc >> 6;

  const int srow = lane >> 3;
  const int sgr  = (lane & 7) ^ srow;

  auto stageA = [&](int buf, int h, int t) {
    const _Float16* src = Ab + (size_t)(h * 128 + wave * 8 + srow) * lda + t * 64 + sgr * 8;
    gld_lds16(&As[buf][h * 128 + wave * 8][0], src);
    gld_lds16(&As[buf][h * 128 + 64 + wave * 8][0], src + (size_t)64 * lda);
  };
  auto stageB = [&](int buf, int h, int t) {
    const _Float16* src = Bb + (size_t)(h * 128 + wave * 8 + srow) * ldb + t * 64 + sgr * 8;
    gld_lds16(&Bs[buf][h * 128 + wave * 8][0], src);
    gld_lds16(&Bs[buf][h * 128 + 64 + wave * 8][0], src + (size_t)64 * ldb);
  };

  const int fr = lane & 15, sq = lane >> 4, fx = fr & 7;
  half8 af[4][2], bLo[2][2], bHi[2][2];
  f32x4 acc[8][4];
  const f32x4 vzero = {0.f, 0.f, 0.f, 0.f};
  #pragma unroll
  for (int f = 0; f < 8; ++f)
    #pragma unroll
    for (int j = 0; j < 4; ++j)
      acc[f][j] = vzero;

  auto dsA = [&](int buf, int mh) {
    #pragma unroll
    for (int i = 0; i < 4; ++i)
      #pragma unroll
      for (int ks = 0; ks < 2; ++ks)
        af[i][ks] = *(const half8*)&As[buf][wr * 128 + mh * 64 + i * 16 + fr]
                                          [((ks * 4 + sq) ^ fx) * 8];
  };
  auto dsBlo = [&](int buf) {
    #pragma unroll
    for (int jj = 0; jj < 2; ++jj)
      #pragma unroll
      for (int ks = 0; ks < 2; ++ks)
        bLo[jj][ks] = *(const half8*)&Bs[buf][wc * 64 + jj * 16 + fr]
                                            [((ks * 4 + sq) ^ fx) * 8];
  };
  auto dsBhi = [&](int buf) {
    #pragma unroll
    for (int jj = 0; jj < 2; ++jj)
      #pragma unroll
      for (int ks = 0; ks < 2; ++ks)
        bHi[jj][ks] = *(const half8*)&Bs[buf][wc * 64 + 32 + jj * 16 + fr]
                                            [((ks * 4 + sq) ^ fx) * 8];
  };
  auto mQlo = [&](int fb) {
    __builtin_amdgcn_s_setprio(1);
    #pragma unroll
    for (int i = 0; i < 4; ++i)
      #pragma unroll
      for (int jj = 0; jj < 2; ++jj)
        #pragma unroll
        for (int ks = 0; ks < 2; ++ks)
          acc[fb + i][jj] = __builtin_amdgcn_mfma_f32_16x16x32_f16(
              af[i][ks], bLo[jj][ks], acc[fb + i][jj], 0, 0, 0);
    __builtin_amdgcn_s_setprio(0);
  };
  auto mQhi = [&](int fb) {
    __builtin_amdgcn_s_setprio(1);
    #pragma unroll
    for (int i = 0; i < 4; ++i)
      #pragma unroll
      for (int jj = 0; jj < 2; ++jj)
        #pragma unroll
        for (int ks = 0; ks < 2; ++ks)
          acc[fb + i][2 + jj] = __builtin_amdgcn_mfma_f32_16x16x32_f16(
              af[i][ks], bHi[jj][ks], acc[fb + i][2 + jj], 0, 0, 0);
    __builtin_amdgcn_s_setprio(0);
  };

  stageA(0, 0, 0); stageA(0, 1, 0); stageB(0, 0, 0); stageB(0, 1, 0);
  stageB(1, 0, 1); stageB(1, 1, 1);
  VMCNT4();
  BARRIER();

  for (int T = 0; T < nt; T += 2) {
    const bool pipe = (T + 2 < nt);
    dsA(0, 0); dsBlo(0);
    stageA(1, 0, T + 1);
    BARRIER(); LGKM0(); mQlo(0); BARRIER();
    dsBhi(0);
    stageA(1, 1, T + 1);
    BARRIER(); LGKM0(); mQhi(0); BARRIER();
    dsA(0, 1);
    if (pipe) stageB(0, 0, T + 2);
    BARRIER(); LGKM0(); mQhi(4); BARRIER();
    if (pipe) { stageB(0, 1, T + 2); VMCNT4(); } else { VMCNT0(); }
    BARRIER(); mQlo(4); BARRIER();
    dsA(1, 0); dsBlo(1);
    if (pipe) stageA(0, 0, T + 2);
    BARRIER(); LGKM0(); mQlo(0); BARRIER();
    dsBhi(1);
    if (pipe) stageA(0, 1, T + 2);
    BARRIER(); LGKM0(); mQhi(0); BARRIER();
    dsA(1, 1);
    if (pipe) stageB(1, 0, T + 3);
    BARRIER(); LGKM0(); mQhi(4); BARRIER();
    if (pipe) { stageB(1, 1, T + 3); VMCNT4(); } else { VMCNT0(); }
    BARRIER(); mQlo(4); BARRIER();
  }

  _Float16* dst = C + (size_t)bz * MN;
  #pragma unroll
  for (int f = 0; f < 8; ++f)
    #pragma unroll
    for (int j = 0; j < 4; ++j)
      #pragma unroll
      for (int r = 0; r < 4; ++r) {
        int row = row0 + wr * 128 + f * 16 + sq * 4 + r;
        int col = col0 + wc * 64 + j * 16 + fr;
        dst[(size_t)row * ldc + col] = (_Float16)acc[f][j][r];
      }
}

// ================= 128x128 GEMM (m97 structure) for the small-N GEMMs =================
__global__ __launch_bounds__(256)
void gemm_f16(const _Float16* __restrict__ A, int lda,
              const _Float16* __restrict__ B, int ldb,
              float* __restrict__ Cf, _Float16* __restrict__ Ch, int ldc,
              int Kc, _Float16* __restrict__ Pk, long MN)
{
  __shared__ _Float16 As[128][32];
  __shared__ _Float16 Bs[128][32];
  const int tid = threadIdx.x;
  const int wave = tid >> 6, lane = tid & 63;
  const int wr = wave >> 1, wc = wave & 1;
  const int row0 = blockIdx.x * 128, col0 = blockIdx.y * 128;
  const int kbase = blockIdx.z * Kc;

  const int sr = lane >> 2;
  const int sk = ((lane & 3) ^ ((lane >> 3) & 3)) * 8;

  f32x4 acc[4][4];
  const f32x4 vzero = {0.f, 0.f, 0.f, 0.f};
  #pragma unroll
  for (int i = 0; i < 4; ++i)
    #pragma unroll
    for (int j = 0; j < 4; ++j)
      acc[i][j] = vzero;

  const int fr = lane & 15;
  const int fk = (((lane >> 4) ^ ((fr >> 1) & 3))) * 8;

  for (int k0 = kbase; k0 < kbase + Kc; k0 += 32) {
    #pragma unroll
    for (int c = 0; c < 2; ++c) {
      int rbase = c * 64 + wave * 16;
      gld_lds16(&As[rbase][0], A + (size_t)(row0 + rbase + sr) * lda + k0 + sk);
      gld_lds16(&Bs[rbase][0], B + (size_t)(col0 + rbase + sr) * ldb + k0 + sk);
    }
    __syncthreads();
    half8 af[4], bf[4];
    #pragma unroll
    for (int i = 0; i < 4; ++i)
      af[i] = *(const half8*)&As[wr * 64 + i * 16 + fr][fk];
    #pragma unroll
    for (int j = 0; j < 4; ++j)
      bf[j] = *(const half8*)&Bs[wc * 64 + j * 16 + fr][fk];
    #pragma unroll
    for (int i = 0; i < 4; ++i)
      #pragma unroll
      for (int j = 0; j < 4; ++j)
        acc[i][j] = __builtin_amdgcn_mfma_f32_16x16x32_f16(af[i], bf[j], acc[i][j], 0, 0, 0);
    __syncthreads();
  }

  const int lr = (lane >> 4) * 4;
  const int lc = lane & 15;
  if (Pk) {
    _Float16* dst = Pk + (size_t)blockIdx.z * MN;
    #pragma unroll
    for (int i = 0; i < 4; ++i)
      #pragma unroll
      for (int j = 0; j < 4; ++j)
        #pragma unroll
        for (int r = 0; r < 4; ++r) {
          int row = row0 + wr * 64 + i * 16 + lr + r;
          int col = col0 + wc * 64 + j * 16 + lc;
          dst[(size_t)row * ldc + col] = (_Float16)acc[i][j][r];
        }
    return;
  }
  #pragma unroll
  for (int i = 0; i < 4; ++i)
    #pragma unroll
    for (int j = 0; j < 4; ++j)
      #pragma unroll
      for (int r = 0; r < 4; ++r) {
        int row = row0 + wr * 64 + i * 16 + lr + r;
        int col = col0 + wc * 64 + j * 16 + lc;
        float v = acc[i][j][r];
        if (Cf) Cf[(size_t)row * ldc + col] = v;
        if (Ch) Ch[(size_t)row * ldc + col] = (_Float16)v;
      }
}

// ---------------- split-K reduce: Y = rowscale(row) * sum_z Pk[z]; writes f32/f16.
// Optional fused BN partial stats (psum/psq != null): per-block column partial
// sums of the f16-rounded outputs. Requires (gridDim*blockDim*4) % C == 0 so each
// thread's 4 columns are fixed across the grid-stride loop (true for C=256/512
// at grid 1536 x 256).
__global__ __launch_bounds__(256)
void reduce_splitk(const _Float16* __restrict__ Pk, long MN, int S, int cshift,
                   const float* __restrict__ rowscale,
                   float* __restrict__ Yf, _Float16* __restrict__ Yh,
                   float* __restrict__ psum, float* __restrict__ psq, int C)
{
  long n4 = MN >> 2;
  float bs[4] = {0.f, 0.f, 0.f, 0.f}, bq[4] = {0.f, 0.f, 0.f, 0.f};
  for (long i = (long)blockIdx.x * 256 + threadIdx.x; i < n4; i += (long)gridDim.x * 256) {
    float s0 = 0, s1 = 0, s2 = 0, s3 = 0;
    for (int z = 0; z < S; ++z) {
      half4v p = ((const half4v*)(Pk + (size_t)z * MN))[i];
      s0 += (float)p[0]; s1 += (float)p[1]; s2 += (float)p[2]; s3 += (float)p[3];
    }
    if (rowscale) {
      float sc = rowscale[(i * 4) >> cshift];
      s0 *= sc; s1 *= sc; s2 *= sc; s3 *= sc;
    }
    if (Yf) {
      float4 o; o.x = s0; o.y = s1; o.z = s2; o.w = s3;
      ((float4*)Yf)[i] = o;
    }
    if (Yh) {
      half4v o;
      o[0] = (_Float16)s0; o[1] = (_Float16)s1; o[2] = (_Float16)s2; o[3] = (_Float16)s3;
      ((half4v*)Yh)[i] = o;
      if (psum) {
        #pragma unroll
        for (int e = 0; e < 4; ++e) {
          float v = (float)o[e];
          bs[e] += v; bq[e] += v * v;
        }
      }
    }
  }
  if (psum) {
    __shared__ float ls[256][4], lq[256][4];
    const int t = threadIdx.x;
    #pragma unroll
    for (int e = 0; e < 4; ++e) { ls[t][e] = bs[e]; lq[t][e] = bq[e]; }
    __syncthreads();
    const int cg = C >> 2;                 // threads owning distinct col-groups
    if (t < cg) {
      float ss[4] = {0, 0, 0, 0}, qq[4] = {0, 0, 0, 0};
      for (int g = 0; g < 256 / cg; ++g)
        #pragma unroll
        for (int e = 0; e < 4; ++e) {
          ss[e] += ls[t + g * cg][e];
          qq[e] += lq[t + g * cg][e];
        }
      #pragma unroll
      for (int e = 0; e < 4; ++e) {
        psum[(size_t)blockIdx.x * C + t * 4 + e] = ss[e];
        psq[(size_t)blockIdx.x * C + t * 4 + e] = qq[e];
      }
    }
  }
}

// ---------------- merged: degree+convert (blocks 0..NROW-1) and bitmask (NROW..)
__global__ __launch_bounds__(256)
void prep_adj(const float* __restrict__ Aglo, _Float16* __restrict__ Ah,
              float* __restrict__ dis, const float* __restrict__ adj,
              uint32_t* __restrict__ bits)
{
  if (blockIdx.x < NROW) {
    const int row = blockIdx.x;
    const float* a = Aglo + (size_t)row * NROW;
    _Float16* o = Ah + (size_t)row * NROW;
    float s = 0.f;
    #pragma unroll
    for (int it = 0; it < 6; ++it) {
      int j = it * 1024 + threadIdx.x * 4;
      float4 v = *(const float4*)&a[j];
      s += v.x + v.y + v.z + v.w;
      half4v h;
      h[0] = (_Float16)v.x; h[1] = (_Float16)v.y; h[2] = (_Float16)v.z; h[3] = (_Float16)v.w;
      *(half4v*)&o[j] = h;
    }
    #pragma unroll
    for (int off = 32; off; off >>= 1) s += __shfl_xor(s, off);
    __shared__ float red[4];
    if ((threadIdx.x & 63) == 0) red[threadIdx.x >> 6] = s;
    __syncthreads();
    if (threadIdx.x == 0) {
      float d = red[0] + red[1] + red[2] + red[3];
      dis[row] = (d > 0.f) ? rsqrtf(fmaxf(d, 1e-12f)) : 0.f;
    }
  } else {
    const int row = blockIdx.x - NROW;
    const int w = threadIdx.x;
    if (w < 192) {
      const float* a = adj + (size_t)row * NROW + w * 32;
      uint32_t m = 0;
      #pragma unroll
      for (int q = 0; q < 8; ++q) {
        float4 x = *(const float4*)&a[q * 4];
        m |= (x.x != 0.f ? 1u : 0u) << (q * 4 + 0);
        m |= (x.y != 0.f ? 1u : 0u) << (q * 4 + 1);
        m |= (x.z != 0.f ? 1u : 0u) << (q * 4 + 2);
        m |= (x.w != 0.f ? 1u : 0u) << (q * 4 + 3);
      }
      bits[(size_t)row * 192 + w] = m;
    }
  }
}

// ---------------- one-shot weight conversion: 13 segments in a single launch
struct WConv {
  const float* src[13];
  _Float16* dst[13];
  int n4[13];
  float scale[13];
};
__global__ __launch_bounds__(256)
void convert_weights(WConv w)
{
  const int seg = blockIdx.x >> 4;
  const int bi = blockIdx.x & 15;
  const float* x = w.src[seg];
  _Float16* y = w.dst[seg];
  const float sc = w.scale[seg];
  const int n4 = w.n4[seg];
  for (int i = bi * 256 + threadIdx.x; i < n4; i += 16 * 256) {
    float4 v = ((const float4*)x)[i];
    half4v o;
    o[0] = (_Float16)(v.x * sc); o[1] = (_Float16)(v.y * sc);
    o[2] = (_Float16)(v.z * sc); o[3] = (_Float16)(v.w * sc);
    ((half4v*)y)[i] = o;
  }
}

// ---------------- dst[c][r] = f16(src[r][c] * rowscale[r]); src f32 [R,C], dst [C,R]
__global__ __launch_bounds__(256)
void transpose_scale_f16(const float* __restrict__ src, const float* __restrict__ rowscale,
                         _Float16* __restrict__ dst, int R, int C)
{
  __shared__ _Float16 tile[64][72];
  const int c0 = blockIdx.x * 64, r0 = blockIdx.y * 64;
  const int tx4 = (threadIdx.x & 15) * 4, ty = threadIdx.x >> 4;
  #pragma unroll
  for (int p = 0; p < 4; ++p) {
    int r = p * 16 + ty;
    float4 v = *(const float4*)&src[(size_t)(r0 + r) * C + c0 + tx4];
    float sc = rowscale ? rowscale[r0 + r] : 1.0f;
    tile[tx4 + 0][r] = (_Float16)(v.x * sc);
    tile[tx4 + 1][r] = (_Float16)(v.y * sc);
    tile[tx4 + 2][r] = (_Float16)(v.z * sc);
    tile[tx4 + 3][r] = (_Float16)(v.w * sc);
  }
  __syncthreads();
  #pragma unroll
  for (int p = 0; p < 4; ++p) {
    int c = p * 16 + ty;
    half4v o;
    o[0] = tile[c][tx4 + 0];
    o[1] = tile[c][tx4 + 1];
    o[2] = tile[c][tx4 + 2];
    o[3] = tile[c][tx4 + 3];
    *(half4v*)&dst[(size_t)(c0 + c) * R + r0 + tx4] = o;
  }
}

// ---------------- in-place masked softmax over f16 scores; writes UNNORMALIZED exp
// and linv[row] = 1/sum (normalization folded into PV reduce rowscale)
__global__ __launch_bounds__(256)
void softmax_mask16(_Float16* __restrict__ Sf, const uint32_t* __restrict__ bits,
                    float* __restrict__ linv)
{
  const int row = blockIdx.x;
  _Float16* s = Sf + (size_t)row * NROW;
  const uint32_t* b = bits + (size_t)row * 192;
  const int tid = threadIdx.x;
  float v[24];
  float m = NEG_INF;
  #pragma unroll
  for (int it = 0; it < 3; ++it) {
    int j = it * 2048 + tid * 8;
    half8 sv = *(const half8*)&s[j];
    uint32_t w = (b[j >> 5] >> (j & 31)) & 0xffu;
    #pragma unroll
    for (int e = 0; e < 8; ++e) {
      float x = ((w >> e) & 1u) ? (float)sv[e] : NEG_INF;
      v[it * 8 + e] = x;
      m = fmaxf(m, x);
    }
  }
  #pragma unroll
  for (int off = 32; off; off >>= 1) m = fmaxf(m, __shfl_xor(m, off));
  __shared__ float red[4];
  const int lane = tid & 63, wave = tid >> 6;
  if (lane == 0) red[wave] = m;
  __syncthreads();
  m = fmaxf(fmaxf(red[0], red[1]), fmaxf(red[2], red[3]));
  __syncthreads();
  float l = 0.f;
  #pragma unroll
  for (int k = 0; k < 24; ++k) {
    float e = (v[k] == NEG_INF) ? 0.f : __expf(v[k] - m);
    v[k] = e; l += e;
  }
  #pragma unroll
  for (int off = 32; off; off >>= 1) l += __shfl_xor(l, off);
  if (lane == 0) red[wave] = l;
  __syncthreads();
  l = red[0] + red[1] + red[2] + red[3];
  if (tid == 0) linv[row] = (l > 0.f) ? (1.f / l) : 0.f;
  #pragma unroll
  for (int it = 0; it < 3; ++it) {
    int j = it * 2048 + tid * 8;
    half8 o;
    #pragma unroll
    for (int e = 0; e < 8; ++e) o[e] = (_Float16)v[it * 8 + e];
    *(half8*)&s[j] = o;
  }
}

// ---------------- BN partial sums, vectorized half8, 64 rows per block (embed path)
__global__ __launch_bounds__(256)
void bn_partial(const _Float16* __restrict__ X, int C,
                float* __restrict__ psum, float* __restrict__ psq)
{
  const int b = blockIdx.x;
  const int t = threadIdx.x;
  const int tpc = C >> 3;
  const int ng = 256 / tpc;
  const int g = t / tpc, c8 = (t % tpc) * 8;
  const int rpg = 64 / ng;
  const _Float16* x = X + (size_t)b * 64 * C;
  float s[8], q[8];
  #pragma unroll
  for (int e = 0; e < 8; ++e) { s[e] = 0.f; q[e] = 0.f; }
  for (int r = g * rpg; r < (g + 1) * rpg; ++r) {
    half8 v = *(const half8*)&x[(size_t)r * C + c8];
    #pragma unroll
    for (int e = 0; e < 8; ++e) {
      float f = (float)v[e];
      s[e] += f; q[e] += f * f;
    }
  }
  __shared__ float ls[256][8], lq[256][8];
  #pragma unroll
  for (int e = 0; e < 8; ++e) { ls[t][e] = s[e]; lq[t][e] = q[e]; }
  __syncthreads();
  for (int u = t; u < C; u += 256) {
    float ss = 0, qq = 0;
    for (int gg = 0; gg < ng; ++gg) {
      ss += ls[gg * tpc + (u >> 3)][u & 7];
      qq += lq[gg * tpc + (u >> 3)][u & 7];
    }
    psum[b * C + u] = ss; psq[b * C + u] = qq;
  }
}

__global__ void bn_finalize(const float* __restrict__ psum, const float* __restrict__ psq,
                            int C, int nb,
                            const float* __restrict__ g, const float* __restrict__ beta,
                            float* __restrict__ scale, float* __restrict__ shift)
{
  int c = threadIdx.x + blockIdx.x * blockDim.x;
  if (c >= C) return;
  float s = 0, q = 0;
  for (int b = 0; b < nb; ++b) { s += psum[(size_t)b * C + c]; q += psq[(size_t)b * C + c]; }
  const float invN = 1.0f / 6144.0f;
  float mean = s * invN;
  float var = q * invN - mean * mean;
  float rstd = rsqrtf(fmaxf(var, 0.f) + 1e-5f);
  float sc = g[c] * rstd;
  scale[c] = sc;
  shift[c] = beta[c] - mean * sc;
}

// ---------------- y = relu?(x*scale[c]+shift[c]) + residual(f16); f16 input
__global__ __launch_bounds__(256)
void bn_apply(const _Float16* __restrict__ X, const float* __restrict__ scale,
              const float* __restrict__ shift, const _Float16* __restrict__ residual,
              float* __restrict__ Yf, _Float16* __restrict__ Yh,
              int Cmask, long total, int do_relu)
{
  for (long i = (long)blockIdx.x * 256 + threadIdx.x; i < total; i += (long)gridDim.x * 256) {
    int c = (int)(i & Cmask);
    float v = (float)X[i] * scale[c] + shift[c];
    if (do_relu) v = fmaxf(v, 0.f);
    if (residual) v += (float)residual[i];
    if (Yf) Yf[i] = v;
    if (Yh) Yh[i] = (_Float16)v;
  }
}

extern "C" void kernel_launch(void* const* d_in, const int* in_sizes, int n_in,
                              void* d_out, int out_size, void* d_ws, size_t ws_size,
                              hipStream_t stream)
{
  (void)in_sizes; (void)n_in; (void)out_size; (void)ws_size;
  const float* X     = (const float*)d_in[0];
  const float* adj   = (const float*)d_in[1];
  const float* adjg  = (const float*)d_in[2];
  const float* Wp    = (const float*)d_in[3];
  const float* gp    = (const float*)d_in[5];
  const float* betap = (const float*)d_in[6];

  float* out_h     = (float*)d_out;                       // [6144,256]
  float* out_embed = out_h + (size_t)NROW * DOUT;         // [6144,512]

  char* base = (char*)d_ws;
  size_t off = 0;
  auto alloc = [&](size_t bytes) -> void* {
    void* p = base + off;
    off += (bytes + 255) & ~(size_t)255;
    return p;
  };

  const long MN512 = (long)NROW * 512;

  _Float16* Ag  = (_Float16*)alloc((size_t)NROW * NROW * 2);   // adjg f16; reused as scores Sf
  _Float16* Sf  = Ag;
  uint32_t* bits = (uint32_t*)alloc((size_t)NROW * 192 * 4);
  _Float16* Pk  = (_Float16*)alloc((size_t)8 * MN512 * 2);     // split-K partials (f16)
  _Float16* XsT = (_Float16*)alloc((size_t)HDIM * NROW * 2);
  _Float16* Yh16 = (_Float16*)alloc((size_t)NROW * HDIM * 2);
  _Float16* Wph = (_Float16*)alloc((size_t)HDIM * HDIM * 2);
  _Float16* QKVW[3];
  for (int i = 0; i < 3; ++i) QKVW[i] = (_Float16*)alloc((size_t)1536 * HDIM * 2);
  _Float16* Woh[3];
  Woh[0] = (_Float16*)alloc((size_t)512 * 512 * 2);
  Woh[1] = (_Float16*)alloc((size_t)512 * 512 * 2);
  Woh[2] = (_Float16*)alloc((size_t)256 * 512 * 2);
  _Float16* QKh  = (_Float16*)alloc((size_t)NROW * 1024 * 2);  // Q,K only
  _Float16* VTh  = (_Float16*)alloc((size_t)HDIM * NROW * 2);
  _Float16* AVh  = (_Float16*)alloc((size_t)NROW * HDIM * 2);
  _Float16* xh   = (_Float16*)alloc((size_t)NROW * HDIM * 2);
  _Float16* hb16A = (_Float16*)alloc((size_t)NROW * HDIM * 2);
  _Float16* hb16B = (_Float16*)alloc((size_t)NROW * HDIM * 2);
  float* dis  = (float*)alloc((size_t)NROW * 4);
  float* linv = (float*)alloc((size_t)NROW * 4);
  float* psum = (float*)alloc((size_t)1536 * 512 * 4);
  float* psq  = (float*)alloc((size_t)1536 * 512 * 4);
  float* bnsc = (float*)alloc(512 * 4);
  float* bnsh = (float*)alloc(512 * 4);

  const float qk_scale = 0.21022410381342863f;  // 512^(-1/4); folded into both Wq and Wk

  prep_adj<<<2 * NROW, 256, 0, stream>>>(adjg, Ag, dis, adj, bits);
  transpose_scale_f16<<<dim3(8, 96), 256, 0, stream>>>(X, dis, XsT, NROW, HDIM);

  {
    WConv w;
    int seg = 0;
    w.src[seg] = Wp; w.dst[seg] = Wph; w.n4[seg] = 512 * 512 / 4; w.scale[seg] = 1.f; ++seg;
    for (int i = 0; i < 3; ++i) {
      int o = (i < 2) ? 512 : 256;
      w.src[seg] = (const float*)d_in[7 + i * 7 + 0]; w.dst[seg] = QKVW[i];
      w.n4[seg] = 512 * 512 / 4; w.scale[seg] = qk_scale; ++seg;
      w.src[seg] = (const float*)d_in[7 + i * 7 + 1]; w.dst[seg] = QKVW[i] + 512 * 512;
      w.n4[seg] = 512 * 512 / 4; w.scale[seg] = qk_scale; ++seg;
      w.src[seg] = (const float*)d_in[7 + i * 7 + 2]; w.dst[seg] = QKVW[i] + 2 * 512 * 512;
      w.n4[seg] = 512 * 512 / 4; w.scale[seg] = 1.f; ++seg;
      w.src[seg] = (const float*)d_in[7 + i * 7 + 3]; w.dst[seg] = Woh[i];
      w.n4[seg] = o * 512 / 4; w.scale[seg] = 1.f; ++seg;
    }
    convert_weights<<<13 * 16, 256, 0, stream>>>(w);
  }

  // ---- embedding: h = BN( rowscale(dis) * (Ag @ XsT^T) @ Wp^T )   (bias cancels in BN)
  gemm256<<<dim3(24, 2, 8), 512, 0, stream>>>(Ag, NROW, XsT, NROW, Pk, 512, 768, MN512);
  reduce_splitk<<<1536, 256, 0, stream>>>(Pk, MN512, 8, 9, dis, nullptr, Yh16,
                                          nullptr, nullptr, 0);
  gemm_f16<<<dim3(48, 4), 256, 0, stream>>>(Yh16, HDIM, Wph, HDIM, nullptr, xh, HDIM,
                                            512, nullptr, 0);
  bn_partial<<<96, 256, 0, stream>>>(xh, 512, psum, psq);
  bn_finalize<<<2, 256, 0, stream>>>(psum, psq, 512, 96, gp, betap, bnsc, bnsh);
  bn_apply<<<2048, 256, 0, stream>>>(xh, bnsc, bnsh, nullptr, out_embed, hb16A,
                                     511, MN512, 0);

  _Float16* hbuf[2] = {hb16A, hb16B};
  int cur = 0;
  for (int i = 0; i < 3; ++i) {
    int o = (i < 2) ? 512 : 256;
    const float* gl = (const float*)d_in[7 + i * 7 + 5];
    const float* bl = (const float*)d_in[7 + i * 7 + 6];
    _Float16* hin = hbuf[cur];

    // Q,K projection: [6144,1024]
    gemm_f16<<<dim3(48, 8), 256, 0, stream>>>(hin, HDIM, QKVW[i], HDIM, nullptr, QKh, 1024,
                                              512, nullptr, 0);
    // V^T directly: C[512,6144] = Wv[512,512] * h[6144,512]^T
    gemm_f16<<<dim3(4, 48), 256, 0, stream>>>(QKVW[i] + 2 * 512 * 512, HDIM, hin, HDIM,
                                              nullptr, VTh, NROW, 512, nullptr, 0);
    // raw scores (f16), then in-place masked softmax (unnormalized exp + linv)
    gemm256<<<dim3(24, 24), 512, 0, stream>>>(QKh, 1024, QKh + 512, 1024, Sf, NROW, 512, 0);
    softmax_mask16<<<NROW, 256, 0, stream>>>(Sf, bits, linv);
    // attn @ V (split-K 8), normalization via rowscale=linv in reduce
    gemm256<<<dim3(24, 2, 8), 512, 0, stream>>>(Sf, NROW, VTh, NROW, Pk, 512, 768, MN512);
    reduce_splitk<<<1536, 256, 0, stream>>>(Pk, MN512, 8, 9, linv, nullptr, AVh,
                                            nullptr, nullptr, 0);
    // @ Wo^T (split-K 4; bias cancels in BN); fused BN partial stats
    long MNo = (long)NROW * o;
    gemm_f16<<<dim3(48, o / 128, 4), 256, 0, stream>>>(AVh, HDIM, Woh[i], HDIM,
                                                       nullptr, nullptr, o, 128, Pk, MNo);
    reduce_splitk<<<1536, 256, 0, stream>>>(Pk, MNo, 4, 0, nullptr, nullptr, xh,
                                            psum, psq, o);
    bn_finalize<<<2, 256, 0, stream>>>(psum, psq, o, 1536, gl, bl, bnsc, bnsh);
    if (i < 2) {
      bn_apply<<<2048, 256, 0, stream>>>(xh, bnsc, bnsh, hin, nullptr, hbuf[cur ^ 1],
                                         o - 1, (long)NROW * o, 1);
      cur ^= 1;
    } else {
      bn_apply<<<2048, 256, 0, stream>>>(xh, bnsc, bnsh, nullptr, out_h, nullptr,
                                         o - 1, (long)NROW * o, 1);
    }
  }
}

// Round 10
// 937.468 us; speedup vs baseline: 2.2163x; 2.2163x over previous
//
#include <hip/hip_runtime.h>
#include <cstdint>

#define NROW 6144
#define HDIM 512
#define DOUT 256
#define NEG_INF (-__builtin_inff())

typedef _Float16 half8 __attribute__((ext_vector_type(8)));
typedef _Float16 half4v __attribute__((ext_vector_type(4)));
typedef float f32x4 __attribute__((ext_vector_type(4)));

#define BARRIER() asm volatile("s_barrier" ::: "memory")
#define LGKM0()   asm volatile("s_waitcnt lgkmcnt(0)" ::: "memory")
#define VMCNT4()  asm volatile("s_waitcnt vmcnt(4)" ::: "memory")
#define VMCNT0()  asm volatile("s_waitcnt vmcnt(0)" ::: "memory")

__device__ __forceinline__ void gld_lds16(void* lds, const void* g) {
  __builtin_amdgcn_global_load_lds(
      (const __attribute__((address_space(1))) void*)g,
      (__attribute__((address_space(3))) void*)lds, 16, 0, 0);
}

// ============== gemm256: 8-phase 256x256 GEMM (proven r5-r7 schedule) ==============
// C[M,N] = A[M,K]*B[N,K]^T (row-major, f16 in, f32 acc, f16 out). Stage ledger:
// ph1 A(1,h0,T+1) ph2 A(1,h1,T+1) ph3 B(0,h0,T+2) ph4 B(0,h1,T+2)
// ph5 A(0,h0,T+2) ph6 A(0,h1,T+2) ph7 B(1,h0,T+3) ph8 B(1,h1,T+3); vmcnt(4) at
// ph4/ph8; tail vmcnt(0). LDS swizzle: 16B slot s of row r holds logical s^(r&7).
__global__ __launch_bounds__(512, 2)
void gemm256(const _Float16* __restrict__ A, int lda,
             const _Float16* __restrict__ B, int ldb,
             _Float16* __restrict__ C, int ldc, int Kc, long MN)
{
  __shared__ _Float16 As[2][256][64];
  __shared__ _Float16 Bs[2][256][64];
  const int tid = threadIdx.x;
  const int wave = tid >> 6, lane = tid & 63;
  const int wr = wave >> 2, wc = wave & 3;

  const int gx = gridDim.x, gy = gridDim.y;
  const int nwg = gx * gy * gridDim.z;
  int lin = (blockIdx.z * gy + blockIdx.y) * gx + blockIdx.x;
  int swz = (nwg % 8 == 0) ? ((lin % 8) * (nwg >> 3) + (lin >> 3)) : lin;
  const int bx = swz % gx, by = (swz / gx) % gy, bz = swz / (gx * gy);
  const int row0 = bx * 256, col0 = by * 256;
  const _Float16* Ab = A + (size_t)row0 * lda + (size_t)bz * Kc;
  const _Float16* Bb = B + (size_t)col0 * ldb + (size_t)bz * Kc;
  const int nt = Kc >> 6;

  const int srow = lane >> 3;
  const int sgr  = (lane & 7) ^ srow;

  auto stageA = [&](int buf, int h, int t) {
    const _Float16* src = Ab + (size_t)(h * 128 + wave * 8 + srow) * lda + t * 64 + sgr * 8;
    gld_lds16(&As[buf][h * 128 + wave * 8][0], src);
    gld_lds16(&As[buf][h * 128 + 64 + wave * 8][0], src + (size_t)64 * lda);
  };
  auto stageB = [&](int buf, int h, int t) {
    const _Float16* src = Bb + (size_t)(h * 128 + wave * 8 + srow) * ldb + t * 64 + sgr * 8;
    gld_lds16(&Bs[buf][h * 128 + wave * 8][0], src);
    gld_lds16(&Bs[buf][h * 128 + 64 + wave * 8][0], src + (size_t)64 * ldb);
  };

  const int fr = lane & 15, sq = lane >> 4, fx = fr & 7;
  half8 af[4][2], bLo[2][2], bHi[2][2];
  f32x4 acc[8][4];
  const f32x4 vzero = {0.f, 0.f, 0.f, 0.f};
  #pragma unroll
  for (int f = 0; f < 8; ++f)
    #pragma unroll
    for (int j = 0; j < 4; ++j)
      acc[f][j] = vzero;

  auto dsA = [&](int buf, int mh) {
    #pragma unroll
    for (int i = 0; i < 4; ++i)
      #pragma unroll
      for (int ks = 0; ks < 2; ++ks)
        af[i][ks] = *(const half8*)&As[buf][wr * 128 + mh * 64 + i * 16 + fr]
                                          [((ks * 4 + sq) ^ fx) * 8];
  };
  auto dsBlo = [&](int buf) {
    #pragma unroll
    for (int jj = 0; jj < 2; ++jj)
      #pragma unroll
      for (int ks = 0; ks < 2; ++ks)
        bLo[jj][ks] = *(const half8*)&Bs[buf][wc * 64 + jj * 16 + fr]
                                            [((ks * 4 + sq) ^ fx) * 8];
  };
  auto dsBhi = [&](int buf) {
    #pragma unroll
    for (int jj = 0; jj < 2; ++jj)
      #pragma unroll
      for (int ks = 0; ks < 2; ++ks)
        bHi[jj][ks] = *(const half8*)&Bs[buf][wc * 64 + 32 + jj * 16 + fr]
                                            [((ks * 4 + sq) ^ fx) * 8];
  };
  auto mQlo = [&](int fb) {
    __builtin_amdgcn_s_setprio(1);
    #pragma unroll
    for (int i = 0; i < 4; ++i)
      #pragma unroll
      for (int jj = 0; jj < 2; ++jj)
        #pragma unroll
        for (int ks = 0; ks < 2; ++ks)
          acc[fb + i][jj] = __builtin_amdgcn_mfma_f32_16x16x32_f16(
              af[i][ks], bLo[jj][ks], acc[fb + i][jj], 0, 0, 0);
    __builtin_amdgcn_s_setprio(0);
  };
  auto mQhi = [&](int fb) {
    __builtin_amdgcn_s_setprio(1);
    #pragma unroll
    for (int i = 0; i < 4; ++i)
      #pragma unroll
      for (int jj = 0; jj < 2; ++jj)
        #pragma unroll
        for (int ks = 0; ks < 2; ++ks)
          acc[fb + i][2 + jj] = __builtin_amdgcn_mfma_f32_16x16x32_f16(
              af[i][ks], bHi[jj][ks], acc[fb + i][2 + jj], 0, 0, 0);
    __builtin_amdgcn_s_setprio(0);
  };

  stageA(0, 0, 0); stageA(0, 1, 0); stageB(0, 0, 0); stageB(0, 1, 0);
  stageB(1, 0, 1); stageB(1, 1, 1);
  VMCNT4();
  BARRIER();

  for (int T = 0; T < nt; T += 2) {
    const bool pipe = (T + 2 < nt);
    dsA(0, 0); dsBlo(0);
    stageA(1, 0, T + 1);
    BARRIER(); LGKM0(); mQlo(0); BARRIER();
    dsBhi(0);
    stageA(1, 1, T + 1);
    BARRIER(); LGKM0(); mQhi(0); BARRIER();
    dsA(0, 1);
    if (pipe) stageB(0, 0, T + 2);
    BARRIER(); LGKM0(); mQhi(4); BARRIER();
    if (pipe) { stageB(0, 1, T + 2); VMCNT4(); } else { VMCNT0(); }
    BARRIER(); mQlo(4); BARRIER();
    dsA(1, 0); dsBlo(1);
    if (pipe) stageA(0, 0, T + 2);
    BARRIER(); LGKM0(); mQlo(0); BARRIER();
    dsBhi(1);
    if (pipe) stageA(0, 1, T + 2);
    BARRIER(); LGKM0(); mQhi(0); BARRIER();
    dsA(1, 1);
    if (pipe) stageB(1, 0, T + 3);
    BARRIER(); LGKM0(); mQhi(4); BARRIER();
    if (pipe) { stageB(1, 1, T + 3); VMCNT4(); } else { VMCNT0(); }
    BARRIER(); mQlo(4); BARRIER();
  }

  _Float16* dst = C + (size_t)bz * MN;
  #pragma unroll
  for (int f = 0; f < 8; ++f)
    #pragma unroll
    for (int j = 0; j < 4; ++j)
      #pragma unroll
      for (int r = 0; r < 4; ++r) {
        int row = row0 + wr * 128 + f * 16 + sq * 4 + r;
        int col = col0 + wc * 64 + j * 16 + fr;
        dst[(size_t)row * ldc + col] = (_Float16)acc[f][j][r];
      }
}

// ================= 128x128 GEMM (m97 structure) for the small-N GEMMs =================
__global__ __launch_bounds__(256)
void gemm_f16(const _Float16* __restrict__ A, int lda,
              const _Float16* __restrict__ B, int ldb,
              float* __restrict__ Cf, _Float16* __restrict__ Ch, int ldc,
              int Kc, _Float16* __restrict__ Pk, long MN)
{
  __shared__ _Float16 As[128][32];
  __shared__ _Float16 Bs[128][32];
  const int tid = threadIdx.x;
  const int wave = tid >> 6, lane = tid & 63;
  const int wr = wave >> 1, wc = wave & 1;
  const int row0 = blockIdx.x * 128, col0 = blockIdx.y * 128;
  const int kbase = blockIdx.z * Kc;

  const int sr = lane >> 2;
  const int sk = ((lane & 3) ^ ((lane >> 3) & 3)) * 8;

  f32x4 acc[4][4];
  const f32x4 vzero = {0.f, 0.f, 0.f, 0.f};
  #pragma unroll
  for (int i = 0; i < 4; ++i)
    #pragma unroll
    for (int j = 0; j < 4; ++j)
      acc[i][j] = vzero;

  const int fr = lane & 15;
  const int fk = (((lane >> 4) ^ ((fr >> 1) & 3))) * 8;

  for (int k0 = kbase; k0 < kbase + Kc; k0 += 32) {
    #pragma unroll
    for (int c = 0; c < 2; ++c) {
      int rbase = c * 64 + wave * 16;
      gld_lds16(&As[rbase][0], A + (size_t)(row0 + rbase + sr) * lda + k0 + sk);
      gld_lds16(&Bs[rbase][0], B + (size_t)(col0 + rbase + sr) * ldb + k0 + sk);
    }
    __syncthreads();
    half8 af[4], bf[4];
    #pragma unroll
    for (int i = 0; i < 4; ++i)
      af[i] = *(const half8*)&As[wr * 64 + i * 16 + fr][fk];
    #pragma unroll
    for (int j = 0; j < 4; ++j)
      bf[j] = *(const half8*)&Bs[wc * 64 + j * 16 + fr][fk];
    #pragma unroll
    for (int i = 0; i < 4; ++i)
      #pragma unroll
      for (int j = 0; j < 4; ++j)
        acc[i][j] = __builtin_amdgcn_mfma_f32_16x16x32_f16(af[i], bf[j], acc[i][j], 0, 0, 0);
    __syncthreads();
  }

  const int lr = (lane >> 4) * 4;
  const int lc = lane & 15;
  if (Pk) {
    _Float16* dst = Pk + (size_t)blockIdx.z * MN;
    #pragma unroll
    for (int i = 0; i < 4; ++i)
      #pragma unroll
      for (int j = 0; j < 4; ++j)
        #pragma unroll
        for (int r = 0; r < 4; ++r) {
          int row = row0 + wr * 64 + i * 16 + lr + r;
          int col = col0 + wc * 64 + j * 16 + lc;
          dst[(size_t)row * ldc + col] = (_Float16)acc[i][j][r];
        }
    return;
  }
  #pragma unroll
  for (int i = 0; i < 4; ++i)
    #pragma unroll
    for (int j = 0; j < 4; ++j)
      #pragma unroll
      for (int r = 0; r < 4; ++r) {
        int row = row0 + wr * 64 + i * 16 + lr + r;
        int col = col0 + wc * 64 + j * 16 + lc;
        float v = acc[i][j][r];
        if (Cf) Cf[(size_t)row * ldc + col] = v;
        if (Ch) Ch[(size_t)row * ldc + col] = (_Float16)v;
      }
}

// ---------------- split-K reduce: Y = rowscale(row) * sum_z Pk[z]; writes f32/f16
__global__ __launch_bounds__(256)
void reduce_splitk(const _Float16* __restrict__ Pk, long MN, int S, int cshift,
                   const float* __restrict__ rowscale,
                   float* __restrict__ Yf, _Float16* __restrict__ Yh)
{
  long n4 = MN >> 2;
  for (long i = (long)blockIdx.x * 256 + threadIdx.x; i < n4; i += (long)gridDim.x * 256) {
    float s0 = 0, s1 = 0, s2 = 0, s3 = 0;
    for (int z = 0; z < S; ++z) {
      half4v p = ((const half4v*)(Pk + (size_t)z * MN))[i];
      s0 += (float)p[0]; s1 += (float)p[1]; s2 += (float)p[2]; s3 += (float)p[3];
    }
    if (rowscale) {
      float sc = rowscale[(i * 4) >> cshift];
      s0 *= sc; s1 *= sc; s2 *= sc; s3 *= sc;
    }
    if (Yf) {
      float4 o; o.x = s0; o.y = s1; o.z = s2; o.w = s3;
      ((float4*)Yf)[i] = o;
    }
    if (Yh) {
      half4v o;
      o[0] = (_Float16)s0; o[1] = (_Float16)s1; o[2] = (_Float16)s2; o[3] = (_Float16)s3;
      ((half4v*)Yh)[i] = o;
    }
  }
}

// ---------------- merged: degree+convert (blocks 0..NROW-1) and bitmask (NROW..)
__global__ __launch_bounds__(256)
void prep_adj(const float* __restrict__ Aglo, _Float16* __restrict__ Ah,
              float* __restrict__ dis, const float* __restrict__ adj,
              uint32_t* __restrict__ bits)
{
  if (blockIdx.x < NROW) {
    const int row = blockIdx.x;
    const float* a = Aglo + (size_t)row * NROW;
    _Float16* o = Ah + (size_t)row * NROW;
    float s = 0.f;
    #pragma unroll
    for (int it = 0; it < 6; ++it) {
      int j = it * 1024 + threadIdx.x * 4;
      float4 v = *(const float4*)&a[j];
      s += v.x + v.y + v.z + v.w;
      half4v h;
      h[0] = (_Float16)v.x; h[1] = (_Float16)v.y; h[2] = (_Float16)v.z; h[3] = (_Float16)v.w;
      *(half4v*)&o[j] = h;
    }
    #pragma unroll
    for (int off = 32; off; off >>= 1) s += __shfl_xor(s, off);
    __shared__ float red[4];
    if ((threadIdx.x & 63) == 0) red[threadIdx.x >> 6] = s;
    __syncthreads();
    if (threadIdx.x == 0) {
      float d = red[0] + red[1] + red[2] + red[3];
      dis[row] = (d > 0.f) ? rsqrtf(fmaxf(d, 1e-12f)) : 0.f;
    }
  } else {
    const int row = blockIdx.x - NROW;
    const int w = threadIdx.x;
    if (w < 192) {
      const float* a = adj + (size_t)row * NROW + w * 32;
      uint32_t m = 0;
      #pragma unroll
      for (int q = 0; q < 8; ++q) {
        float4 x = *(const float4*)&a[q * 4];
        m |= (x.x != 0.f ? 1u : 0u) << (q * 4 + 0);
        m |= (x.y != 0.f ? 1u : 0u) << (q * 4 + 1);
        m |= (x.z != 0.f ? 1u : 0u) << (q * 4 + 2);
        m |= (x.w != 0.f ? 1u : 0u) << (q * 4 + 3);
      }
      bits[(size_t)row * 192 + w] = m;
    }
  }
}

// ---------------- one-shot weight conversion: 13 segments in a single launch
struct WConv {
  const float* src[13];
  _Float16* dst[13];
  int n4[13];
  float scale[13];
};
__global__ __launch_bounds__(256)
void convert_weights(WConv w)
{
  const int seg = blockIdx.x >> 4;
  const int bi = blockIdx.x & 15;
  const float* x = w.src[seg];
  _Float16* y = w.dst[seg];
  const float sc = w.scale[seg];
  const int n4 = w.n4[seg];
  for (int i = bi * 256 + threadIdx.x; i < n4; i += 16 * 256) {
    float4 v = ((const float4*)x)[i];
    half4v o;
    o[0] = (_Float16)(v.x * sc); o[1] = (_Float16)(v.y * sc);
    o[2] = (_Float16)(v.z * sc); o[3] = (_Float16)(v.w * sc);
    ((half4v*)y)[i] = o;
  }
}

// ---------------- dst[c][r] = f16(src[r][c] * rowscale[r]); src f32 [R,C], dst [C,R]
__global__ __launch_bounds__(256)
void transpose_scale_f16(const float* __restrict__ src, const float* __restrict__ rowscale,
                         _Float16* __restrict__ dst, int R, int C)
{
  __shared__ _Float16 tile[64][72];
  const int c0 = blockIdx.x * 64, r0 = blockIdx.y * 64;
  const int tx4 = (threadIdx.x & 15) * 4, ty = threadIdx.x >> 4;
  #pragma unroll
  for (int p = 0; p < 4; ++p) {
    int r = p * 16 + ty;
    float4 v = *(const float4*)&src[(size_t)(r0 + r) * C + c0 + tx4];
    float sc = rowscale ? rowscale[r0 + r] : 1.0f;
    tile[tx4 + 0][r] = (_Float16)(v.x * sc);
    tile[tx4 + 1][r] = (_Float16)(v.y * sc);
    tile[tx4 + 2][r] = (_Float16)(v.z * sc);
    tile[tx4 + 3][r] = (_Float16)(v.w * sc);
  }
  __syncthreads();
  #pragma unroll
  for (int p = 0; p < 4; ++p) {
    int c = p * 16 + ty;
    half4v o;
    o[0] = tile[c][tx4 + 0];
    o[1] = tile[c][tx4 + 1];
    o[2] = tile[c][tx4 + 2];
    o[3] = tile[c][tx4 + 3];
    *(half4v*)&dst[(size_t)(c0 + c) * R + r0 + tx4] = o;
  }
}

// ---------------- in-place masked softmax over f16 scores; writes UNNORMALIZED exp
// and linv[row] = 1/sum (normalization folded into PV reduce rowscale)
__global__ __launch_bounds__(256)
void softmax_mask16(_Float16* __restrict__ Sf, const uint32_t* __restrict__ bits,
                    float* __restrict__ linv)
{
  const int row = blockIdx.x;
  _Float16* s = Sf + (size_t)row * NROW;
  const uint32_t* b = bits + (size_t)row * 192;
  const int tid = threadIdx.x;
  float v[24];
  float m = NEG_INF;
  #pragma unroll
  for (int it = 0; it < 3; ++it) {
    int j = it * 2048 + tid * 8;
    half8 sv = *(const half8*)&s[j];
    uint32_t w = (b[j >> 5] >> (j & 31)) & 0xffu;
    #pragma unroll
    for (int e = 0; e < 8; ++e) {
      float x = ((w >> e) & 1u) ? (float)sv[e] : NEG_INF;
      v[it * 8 + e] = x;
      m = fmaxf(m, x);
    }
  }
  #pragma unroll
  for (int off = 32; off; off >>= 1) m = fmaxf(m, __shfl_xor(m, off));
  __shared__ float red[4];
  const int lane = tid & 63, wave = tid >> 6;
  if (lane == 0) red[wave] = m;
  __syncthreads();
  m = fmaxf(fmaxf(red[0], red[1]), fmaxf(red[2], red[3]));
  __syncthreads();
  float l = 0.f;
  #pragma unroll
  for (int k = 0; k < 24; ++k) {
    float e = (v[k] == NEG_INF) ? 0.f : __expf(v[k] - m);
    v[k] = e; l += e;
  }
  #pragma unroll
  for (int off = 32; off; off >>= 1) l += __shfl_xor(l, off);
  if (lane == 0) red[wave] = l;
  __syncthreads();
  l = red[0] + red[1] + red[2] + red[3];
  if (tid == 0) linv[row] = (l > 0.f) ? (1.f / l) : 0.f;
  #pragma unroll
  for (int it = 0; it < 3; ++it) {
    int j = it * 2048 + tid * 8;
    half8 o;
    #pragma unroll
    for (int e = 0; e < 8; ++e) o[e] = (_Float16)v[it * 8 + e];
    *(half8*)&s[j] = o;
  }
}

// ---------------- BN partial sums, vectorized half8, 64 rows per block
__global__ __launch_bounds__(256)
void bn_partial(const _Float16* __restrict__ X, int C,
                float* __restrict__ psum, float* __restrict__ psq)
{
  const int b = blockIdx.x;
  const int t = threadIdx.x;
  const int tpc = C >> 3;
  const int ng = 256 / tpc;
  const int g = t / tpc, c8 = (t % tpc) * 8;
  const int rpg = 64 / ng;
  const _Float16* x = X + (size_t)b * 64 * C;
  float s[8], q[8];
  #pragma unroll
  for (int e = 0; e < 8; ++e) { s[e] = 0.f; q[e] = 0.f; }
  for (int r = g * rpg; r < (g + 1) * rpg; ++r) {
    half8 v = *(const half8*)&x[(size_t)r * C + c8];
    #pragma unroll
    for (int e = 0; e < 8; ++e) {
      float f = (float)v[e];
      s[e] += f; q[e] += f * f;
    }
  }
  __shared__ float ls[256][8], lq[256][8];
  #pragma unroll
  for (int e = 0; e < 8; ++e) { ls[t][e] = s[e]; lq[t][e] = q[e]; }
  __syncthreads();
  for (int u = t; u < C; u += 256) {
    float ss = 0, qq = 0;
    for (int gg = 0; gg < ng; ++gg) {
      ss += ls[gg * tpc + (u >> 3)][u & 7];
      qq += lq[gg * tpc + (u >> 3)][u & 7];
    }
    psum[b * C + u] = ss; psq[b * C + u] = qq;
  }
}

__global__ void bn_finalize(const float* __restrict__ psum, const float* __restrict__ psq,
                            int C, int nb,
                            const float* __restrict__ g, const float* __restrict__ beta,
                            float* __restrict__ scale, float* __restrict__ shift)
{
  int c = threadIdx.x + blockIdx.x * blockDim.x;
  if (c >= C) return;
  float s = 0, q = 0;
  for (int b = 0; b < nb; ++b) { s += psum[(size_t)b * C + c]; q += psq[(size_t)b * C + c]; }
  const float invN = 1.0f / 6144.0f;
  float mean = s * invN;
  float var = q * invN - mean * mean;
  float rstd = rsqrtf(fmaxf(var, 0.f) + 1e-5f);
  float sc = g[c] * rstd;
  scale[c] = sc;
  shift[c] = beta[c] - mean * sc;
}

// ---------------- y = relu?(x*scale[c]+shift[c]) + residual(f16); f16 input
__global__ __launch_bounds__(256)
void bn_apply(const _Float16* __restrict__ X, const float* __restrict__ scale,
              const float* __restrict__ shift, const _Float16* __restrict__ residual,
              float* __restrict__ Yf, _Float16* __restrict__ Yh,
              int Cmask, long total, int do_relu)
{
  for (long i = (long)blockIdx.x * 256 + threadIdx.x; i < total; i += (long)gridDim.x * 256) {
    int c = (int)(i & Cmask);
    float v = (float)X[i] * scale[c] + shift[c];
    if (do_relu) v = fmaxf(v, 0.f);
    if (residual) v += (float)residual[i];
    if (Yf) Yf[i] = v;
    if (Yh) Yh[i] = (_Float16)v;
  }
}

extern "C" void kernel_launch(void* const* d_in, const int* in_sizes, int n_in,
                              void* d_out, int out_size, void* d_ws, size_t ws_size,
                              hipStream_t stream)
{
  (void)in_sizes; (void)n_in; (void)out_size; (void)ws_size;
  const float* X     = (const float*)d_in[0];
  const float* adj   = (const float*)d_in[1];
  const float* adjg  = (const float*)d_in[2];
  const float* Wp    = (const float*)d_in[3];
  const float* gp    = (const float*)d_in[5];
  const float* betap = (const float*)d_in[6];

  float* out_h     = (float*)d_out;                       // [6144,256]
  float* out_embed = out_h + (size_t)NROW * DOUT;         // [6144,512]

  char* base = (char*)d_ws;
  size_t off = 0;
  auto alloc = [&](size_t bytes) -> void* {
    void* p = base + off;
    off += (bytes + 255) & ~(size_t)255;
    return p;
  };

  const long MN512 = (long)NROW * 512;

  _Float16* Ag  = (_Float16*)alloc((size_t)NROW * NROW * 2);   // adjg f16; reused as scores Sf
  _Float16* Sf  = Ag;
  uint32_t* bits = (uint32_t*)alloc((size_t)NROW * 192 * 4);
  _Float16* Pk  = (_Float16*)alloc((size_t)8 * MN512 * 2);     // split-K partials (f16)
  _Float16* XsT = (_Float16*)alloc((size_t)HDIM * NROW * 2);
  _Float16* Yh16 = (_Float16*)alloc((size_t)NROW * HDIM * 2);
  _Float16* Wph = (_Float16*)alloc((size_t)HDIM * HDIM * 2);
  _Float16* QKVW[3];
  for (int i = 0; i < 3; ++i) QKVW[i] = (_Float16*)alloc((size_t)1536 * HDIM * 2);
  _Float16* Woh[3];
  Woh[0] = (_Float16*)alloc((size_t)512 * 512 * 2);
  Woh[1] = (_Float16*)alloc((size_t)512 * 512 * 2);
  Woh[2] = (_Float16*)alloc((size_t)256 * 512 * 2);
  _Float16* QKh  = (_Float16*)alloc((size_t)NROW * 1024 * 2);  // Q,K only
  _Float16* VTh  = (_Float16*)alloc((size_t)HDIM * NROW * 2);
  _Float16* AVh  = (_Float16*)alloc((size_t)NROW * HDIM * 2);
  _Float16* xh   = (_Float16*)alloc((size_t)NROW * HDIM * 2);
  _Float16* hb16A = (_Float16*)alloc((size_t)NROW * HDIM * 2);
  _Float16* hb16B = (_Float16*)alloc((size_t)NROW * HDIM * 2);
  float* dis  = (float*)alloc((size_t)NROW * 4);
  float* linv = (float*)alloc((size_t)NROW * 4);
  float* psum = (float*)alloc((size_t)96 * 512 * 4);
  float* psq  = (float*)alloc((size_t)96 * 512 * 4);
  float* bnsc = (float*)alloc(512 * 4);
  float* bnsh = (float*)alloc(512 * 4);

  const float qk_scale = 0.21022410381342863f;  // 512^(-1/4); folded into both Wq and Wk

  prep_adj<<<2 * NROW, 256, 0, stream>>>(adjg, Ag, dis, adj, bits);
  transpose_scale_f16<<<dim3(8, 96), 256, 0, stream>>>(X, dis, XsT, NROW, HDIM);

  {
    WConv w;
    int seg = 0;
    w.src[seg] = Wp; w.dst[seg] = Wph; w.n4[seg] = 512 * 512 / 4; w.scale[seg] = 1.f; ++seg;
    for (int i = 0; i < 3; ++i) {
      int o = (i < 2) ? 512 : 256;
      w.src[seg] = (const float*)d_in[7 + i * 7 + 0]; w.dst[seg] = QKVW[i];
      w.n4[seg] = 512 * 512 / 4; w.scale[seg] = qk_scale; ++seg;
      w.src[seg] = (const float*)d_in[7 + i * 7 + 1]; w.dst[seg] = QKVW[i] + 512 * 512;
      w.n4[seg] = 512 * 512 / 4; w.scale[seg] = qk_scale; ++seg;
      w.src[seg] = (const float*)d_in[7 + i * 7 + 2]; w.dst[seg] = QKVW[i] + 2 * 512 * 512;
      w.n4[seg] = 512 * 512 / 4; w.scale[seg] = 1.f; ++seg;
      w.src[seg] = (const float*)d_in[7 + i * 7 + 3]; w.dst[seg] = Woh[i];
      w.n4[seg] = o * 512 / 4; w.scale[seg] = 1.f; ++seg;
    }
    convert_weights<<<13 * 16, 256, 0, stream>>>(w);
  }

  // ---- embedding: h = BN( rowscale(dis) * (Ag @ XsT^T) @ Wp^T )   (bias cancels in BN)
  gemm256<<<dim3(24, 2, 8), 512, 0, stream>>>(Ag, NROW, XsT, NROW, Pk, 512, 768, MN512);
  reduce_splitk<<<1536, 256, 0, stream>>>(Pk, MN512, 8, 9, dis, nullptr, Yh16);
  gemm_f16<<<dim3(48, 4), 256, 0, stream>>>(Yh16, HDIM, Wph, HDIM, nullptr, xh, HDIM,
                                            512, nullptr, 0);
  bn_partial<<<96, 256, 0, stream>>>(xh, 512, psum, psq);
  bn_finalize<<<2, 256, 0, stream>>>(psum, psq, 512, 96, gp, betap, bnsc, bnsh);
  bn_apply<<<2048, 256, 0, stream>>>(xh, bnsc, bnsh, nullptr, out_embed, hb16A,
                                     511, MN512, 0);

  _Float16* hbuf[2] = {hb16A, hb16B};
  int cur = 0;
  for (int i = 0; i < 3; ++i) {
    int o = (i < 2) ? 512 : 256;
    const float* gl = (const float*)d_in[7 + i * 7 + 5];
    const float* bl = (const float*)d_in[7 + i * 7 + 6];
    _Float16* hin = hbuf[cur];

    // Q,K projection: [6144,1024]
    gemm_f16<<<dim3(48, 8), 256, 0, stream>>>(hin, HDIM, QKVW[i], HDIM, nullptr, QKh, 1024,
                                              512, nullptr, 0);
    // V^T directly: C[512,6144] = Wv[512,512] * h[6144,512]^T
    gemm_f16<<<dim3(4, 48), 256, 0, stream>>>(QKVW[i] + 2 * 512 * 512, HDIM, hin, HDIM,
                                              nullptr, VTh, NROW, 512, nullptr, 0);
    // raw scores (f16), then in-place masked softmax (unnormalized exp + linv)
    gemm256<<<dim3(24, 24), 512, 0, stream>>>(QKh, 1024, QKh + 512, 1024, Sf, NROW, 512, 0);
    softmax_mask16<<<NROW, 256, 0, stream>>>(Sf, bits, linv);
    // attn @ V (split-K 8), normalization via rowscale=linv in reduce
    gemm256<<<dim3(24, 2, 8), 512, 0, stream>>>(Sf, NROW, VTh, NROW, Pk, 512, 768, MN512);
    reduce_splitk<<<1536, 256, 0, stream>>>(Pk, MN512, 8, 9, linv, nullptr, AVh);
    // @ Wo^T (split-K 4; bias cancels in BN)
    long MNo = (long)NROW * o;
    gemm_f16<<<dim3(48, o / 128, 4), 256, 0, stream>>>(AVh, HDIM, Woh[i], HDIM,
                                                       nullptr, nullptr, o, 128, Pk, MNo);
    reduce_splitk<<<1536, 256, 0, stream>>>(Pk, MNo, 4, (o == 512) ? 9 : 8, nullptr,
                                            nullptr, xh);
    bn_partial<<<96, 256, 0, stream>>>(xh, o, psum, psq);
    bn_finalize<<<2, 256, 0, stream>>>(psum, psq, o, 96, gl, bl, bnsc, bnsh);
    if (i < 2) {
      bn_apply<<<2048, 256, 0, stream>>>(xh, bnsc, bnsh, hin, nullptr, hbuf[cur ^ 1],
                                         o - 1, (long)NROW * o, 1);
      cur ^= 1;
    } else {
      bn_apply<<<2048, 256, 0, stream>>>(xh, bnsc, bnsh, nullptr, out_h, nullptr,
                                         o - 1, (long)NROW * o, 1);
    }
  }
}

// Round 11
// 909.506 us; speedup vs baseline: 2.2844x; 1.0307x over previous
//
#include <hip/hip_runtime.h>
#include <cstdint>

#define NROW 6144
#define HDIM 512
#define DOUT 256
#define NEG_INF (-__builtin_inff())

typedef _Float16 half8 __attribute__((ext_vector_type(8)));
typedef _Float16 half4v __attribute__((ext_vector_type(4)));
typedef float f32x4 __attribute__((ext_vector_type(4)));

#define BARRIER() asm volatile("s_barrier" ::: "memory")
#define LGKM0()   asm volatile("s_waitcnt lgkmcnt(0)" ::: "memory")
#define VMCNT4()  asm volatile("s_waitcnt vmcnt(4)" ::: "memory")
#define VMCNT0()  asm volatile("s_waitcnt vmcnt(0)" ::: "memory")

__device__ __forceinline__ void gld_lds16(void* lds, const void* g) {
  __builtin_amdgcn_global_load_lds(
      (const __attribute__((address_space(1))) void*)g,
      (__attribute__((address_space(3))) void*)lds, 16, 0, 0);
}

// ============== gemm256: 8-phase 256x256 GEMM (proven r5-r7 schedule) ==============
// C[M,N] = A[M,K]*B[N,K]^T (row-major, f16 in, f32 acc, f16 out). Stage ledger:
// ph1 A(1,h0,T+1) ph2 A(1,h1,T+1) ph3 B(0,h0,T+2) ph4 B(0,h1,T+2)
// ph5 A(0,h0,T+2) ph6 A(0,h1,T+2) ph7 B(1,h0,T+3) ph8 B(1,h1,T+3); vmcnt(4) at
// ph4/ph8; tail vmcnt(0). LDS swizzle: 16B slot s of row r holds logical s^(r&7).
__global__ __launch_bounds__(512, 2)
void gemm256(const _Float16* __restrict__ A, int lda,
             const _Float16* __restrict__ B, int ldb,
             _Float16* __restrict__ C, int ldc, int Kc, long MN)
{
  __shared__ _Float16 As[2][256][64];
  __shared__ _Float16 Bs[2][256][64];
  const int tid = threadIdx.x;
  const int wave = tid >> 6, lane = tid & 63;
  const int wr = wave >> 2, wc = wave & 3;

  const int gx = gridDim.x, gy = gridDim.y;
  const int nwg = gx * gy * gridDim.z;
  int lin = (blockIdx.z * gy + blockIdx.y) * gx + blockIdx.x;
  int swz = (nwg % 8 == 0) ? ((lin % 8) * (nwg >> 3) + (lin >> 3)) : lin;
  const int bx = swz % gx, by = (swz / gx) % gy, bz = swz / (gx * gy);
  const int row0 = bx * 256, col0 = by * 256;
  const _Float16* Ab = A + (size_t)row0 * lda + (size_t)bz * Kc;
  const _Float16* Bb = B + (size_t)col0 * ldb + (size_t)bz * Kc;
  const int nt = Kc >> 6;

  const int srow = lane >> 3;
  const int sgr  = (lane & 7) ^ srow;

  auto stageA = [&](int buf, int h, int t) {
    const _Float16* src = Ab + (size_t)(h * 128 + wave * 8 + srow) * lda + t * 64 + sgr * 8;
    gld_lds16(&As[buf][h * 128 + wave * 8][0], src);
    gld_lds16(&As[buf][h * 128 + 64 + wave * 8][0], src + (size_t)64 * lda);
  };
  auto stageB = [&](int buf, int h, int t) {
    const _Float16* src = Bb + (size_t)(h * 128 + wave * 8 + srow) * ldb + t * 64 + sgr * 8;
    gld_lds16(&Bs[buf][h * 128 + wave * 8][0], src);
    gld_lds16(&Bs[buf][h * 128 + 64 + wave * 8][0], src + (size_t)64 * ldb);
  };

  const int fr = lane & 15, sq = lane >> 4, fx = fr & 7;
  half8 af[4][2], bLo[2][2], bHi[2][2];
  f32x4 acc[8][4];
  const f32x4 vzero = {0.f, 0.f, 0.f, 0.f};
  #pragma unroll
  for (int f = 0; f < 8; ++f)
    #pragma unroll
    for (int j = 0; j < 4; ++j)
      acc[f][j] = vzero;

  auto dsA = [&](int buf, int mh) {
    #pragma unroll
    for (int i = 0; i < 4; ++i)
      #pragma unroll
      for (int ks = 0; ks < 2; ++ks)
        af[i][ks] = *(const half8*)&As[buf][wr * 128 + mh * 64 + i * 16 + fr]
                                          [((ks * 4 + sq) ^ fx) * 8];
  };
  auto dsBlo = [&](int buf) {
    #pragma unroll
    for (int jj = 0; jj < 2; ++jj)
      #pragma unroll
      for (int ks = 0; ks < 2; ++ks)
        bLo[jj][ks] = *(const half8*)&Bs[buf][wc * 64 + jj * 16 + fr]
                                            [((ks * 4 + sq) ^ fx) * 8];
  };
  auto dsBhi = [&](int buf) {
    #pragma unroll
    for (int jj = 0; jj < 2; ++jj)
      #pragma unroll
      for (int ks = 0; ks < 2; ++ks)
        bHi[jj][ks] = *(const half8*)&Bs[buf][wc * 64 + 32 + jj * 16 + fr]
                                            [((ks * 4 + sq) ^ fx) * 8];
  };
  auto mQlo = [&](int fb) {
    __builtin_amdgcn_s_setprio(1);
    #pragma unroll
    for (int i = 0; i < 4; ++i)
      #pragma unroll
      for (int jj = 0; jj < 2; ++jj)
        #pragma unroll
        for (int ks = 0; ks < 2; ++ks)
          acc[fb + i][jj] = __builtin_amdgcn_mfma_f32_16x16x32_f16(
              af[i][ks], bLo[jj][ks], acc[fb + i][jj], 0, 0, 0);
    __builtin_amdgcn_s_setprio(0);
  };
  auto mQhi = [&](int fb) {
    __builtin_amdgcn_s_setprio(1);
    #pragma unroll
    for (int i = 0; i < 4; ++i)
      #pragma unroll
      for (int jj = 0; jj < 2; ++jj)
        #pragma unroll
        for (int ks = 0; ks < 2; ++ks)
          acc[fb + i][2 + jj] = __builtin_amdgcn_mfma_f32_16x16x32_f16(
              af[i][ks], bHi[jj][ks], acc[fb + i][2 + jj], 0, 0, 0);
    __builtin_amdgcn_s_setprio(0);
  };

  stageA(0, 0, 0); stageA(0, 1, 0); stageB(0, 0, 0); stageB(0, 1, 0);
  stageB(1, 0, 1); stageB(1, 1, 1);
  VMCNT4();
  BARRIER();

  for (int T = 0; T < nt; T += 2) {
    const bool pipe = (T + 2 < nt);
    dsA(0, 0); dsBlo(0);
    stageA(1, 0, T + 1);
    BARRIER(); LGKM0(); mQlo(0); BARRIER();
    dsBhi(0);
    stageA(1, 1, T + 1);
    BARRIER(); LGKM0(); mQhi(0); BARRIER();
    dsA(0, 1);
    if (pipe) stageB(0, 0, T + 2);
    BARRIER(); LGKM0(); mQhi(4); BARRIER();
    if (pipe) { stageB(0, 1, T + 2); VMCNT4(); } else { VMCNT0(); }
    BARRIER(); mQlo(4); BARRIER();
    dsA(1, 0); dsBlo(1);
    if (pipe) stageA(0, 0, T + 2);
    BARRIER(); LGKM0(); mQlo(0); BARRIER();
    dsBhi(1);
    if (pipe) stageA(0, 1, T + 2);
    BARRIER(); LGKM0(); mQhi(0); BARRIER();
    dsA(1, 1);
    if (pipe) stageB(1, 0, T + 3);
    BARRIER(); LGKM0(); mQhi(4); BARRIER();
    if (pipe) { stageB(1, 1, T + 3); VMCNT4(); } else { VMCNT0(); }
    BARRIER(); mQlo(4); BARRIER();
  }

  _Float16* dst = C + (size_t)bz * MN;
  #pragma unroll
  for (int f = 0; f < 8; ++f)
    #pragma unroll
    for (int j = 0; j < 4; ++j)
      #pragma unroll
      for (int r = 0; r < 4; ++r) {
        int row = row0 + wr * 128 + f * 16 + sq * 4 + r;
        int col = col0 + wc * 64 + j * 16 + fr;
        dst[(size_t)row * ldc + col] = (_Float16)acc[f][j][r];
      }
}

// ================= 128x128 GEMM (m97 structure) for the small-N GEMMs =================
__global__ __launch_bounds__(256)
void gemm_f16(const _Float16* __restrict__ A, int lda,
              const _Float16* __restrict__ B, int ldb,
              float* __restrict__ Cf, _Float16* __restrict__ Ch, int ldc,
              int Kc, _Float16* __restrict__ Pk, long MN)
{
  __shared__ _Float16 As[128][32];
  __shared__ _Float16 Bs[128][32];
  const int tid = threadIdx.x;
  const int wave = tid >> 6, lane = tid & 63;
  const int wr = wave >> 1, wc = wave & 1;
  const int row0 = blockIdx.x * 128, col0 = blockIdx.y * 128;
  const int kbase = blockIdx.z * Kc;

  const int sr = lane >> 2;
  const int sk = ((lane & 3) ^ ((lane >> 3) & 3)) * 8;

  f32x4 acc[4][4];
  const f32x4 vzero = {0.f, 0.f, 0.f, 0.f};
  #pragma unroll
  for (int i = 0; i < 4; ++i)
    #pragma unroll
    for (int j = 0; j < 4; ++j)
      acc[i][j] = vzero;

  const int fr = lane & 15;
  const int fk = (((lane >> 4) ^ ((fr >> 1) & 3))) * 8;

  for (int k0 = kbase; k0 < kbase + Kc; k0 += 32) {
    #pragma unroll
    for (int c = 0; c < 2; ++c) {
      int rbase = c * 64 + wave * 16;
      gld_lds16(&As[rbase][0], A + (size_t)(row0 + rbase + sr) * lda + k0 + sk);
      gld_lds16(&Bs[rbase][0], B + (size_t)(col0 + rbase + sr) * ldb + k0 + sk);
    }
    __syncthreads();
    half8 af[4], bf[4];
    #pragma unroll
    for (int i = 0; i < 4; ++i)
      af[i] = *(const half8*)&As[wr * 64 + i * 16 + fr][fk];
    #pragma unroll
    for (int j = 0; j < 4; ++j)
      bf[j] = *(const half8*)&Bs[wc * 64 + j * 16 + fr][fk];
    #pragma unroll
    for (int i = 0; i < 4; ++i)
      #pragma unroll
      for (int j = 0; j < 4; ++j)
        acc[i][j] = __builtin_amdgcn_mfma_f32_16x16x32_f16(af[i], bf[j], acc[i][j], 0, 0, 0);
    __syncthreads();
  }

  const int lr = (lane >> 4) * 4;
  const int lc = lane & 15;
  if (Pk) {
    _Float16* dst = Pk + (size_t)blockIdx.z * MN;
    #pragma unroll
    for (int i = 0; i < 4; ++i)
      #pragma unroll
      for (int j = 0; j < 4; ++j)
        #pragma unroll
        for (int r = 0; r < 4; ++r) {
          int row = row0 + wr * 64 + i * 16 + lr + r;
          int col = col0 + wc * 64 + j * 16 + lc;
          dst[(size_t)row * ldc + col] = (_Float16)acc[i][j][r];
        }
    return;
  }
  #pragma unroll
  for (int i = 0; i < 4; ++i)
    #pragma unroll
    for (int j = 0; j < 4; ++j)
      #pragma unroll
      for (int r = 0; r < 4; ++r) {
        int row = row0 + wr * 64 + i * 16 + lr + r;
        int col = col0 + wc * 64 + j * 16 + lc;
        float v = acc[i][j][r];
        if (Cf) Cf[(size_t)row * ldc + col] = v;
        if (Ch) Ch[(size_t)row * ldc + col] = (_Float16)v;
      }
}

// ---------------- split-K reduce: Y = rowscale(row) * sum_z Pk[z]; writes f32/f16
__global__ __launch_bounds__(256)
void reduce_splitk(const _Float16* __restrict__ Pk, long MN, int S, int cshift,
                   const float* __restrict__ rowscale,
                   float* __restrict__ Yf, _Float16* __restrict__ Yh)
{
  long n4 = MN >> 2;
  for (long i = (long)blockIdx.x * 256 + threadIdx.x; i < n4; i += (long)gridDim.x * 256) {
    float s0 = 0, s1 = 0, s2 = 0, s3 = 0;
    for (int z = 0; z < S; ++z) {
      half4v p = ((const half4v*)(Pk + (size_t)z * MN))[i];
      s0 += (float)p[0]; s1 += (float)p[1]; s2 += (float)p[2]; s3 += (float)p[3];
    }
    if (rowscale) {
      float sc = rowscale[(i * 4) >> cshift];
      s0 *= sc; s1 *= sc; s2 *= sc; s3 *= sc;
    }
    if (Yf) {
      float4 o; o.x = s0; o.y = s1; o.z = s2; o.w = s3;
      ((float4*)Yf)[i] = o;
    }
    if (Yh) {
      half4v o;
      o[0] = (_Float16)s0; o[1] = (_Float16)s1; o[2] = (_Float16)s2; o[3] = (_Float16)s3;
      ((half4v*)Yh)[i] = o;
    }
  }
}

// ---------------- fused: degree row-sum -> dis, and f32 -> f16 adjacency convert
__global__ __launch_bounds__(256)
void degree_convert(const float* __restrict__ A, _Float16* __restrict__ Ah,
                    float* __restrict__ dis)
{
  const int row = blockIdx.x;
  const float* a = A + (size_t)row * NROW;
  _Float16* o = Ah + (size_t)row * NROW;
  float s = 0.f;
  #pragma unroll
  for (int it = 0; it < 6; ++it) {
    int j = it * 1024 + threadIdx.x * 4;
    float4 v = *(const float4*)&a[j];
    s += v.x + v.y + v.z + v.w;
    half4v h;
    h[0] = (_Float16)v.x; h[1] = (_Float16)v.y; h[2] = (_Float16)v.z; h[3] = (_Float16)v.w;
    *(half4v*)&o[j] = h;
  }
  #pragma unroll
  for (int off = 32; off; off >>= 1) s += __shfl_xor(s, off);
  __shared__ float red[4];
  if ((threadIdx.x & 63) == 0) red[threadIdx.x >> 6] = s;
  __syncthreads();
  if (threadIdx.x == 0) {
    float d = red[0] + red[1] + red[2] + red[3];
    dis[row] = (d > 0.f) ? rsqrtf(fmaxf(d, 1e-12f)) : 0.f;
  }
}

// ---------------- adj (f32 0/1) -> bitmask [NROW][192] u32; fully coalesced:
// thread t loads float4 at element 4t (wave = 1KB contiguous), builds 4-bit
// nibble, assembles 8 nibbles -> u32 via 3x shfl_xor; 1 store per 8 lanes.
__global__ __launch_bounds__(256)
void build_mask(const float* __restrict__ adj, uint32_t* __restrict__ bits)
{
  const int row = blockIdx.x;
  const float* a = adj + (size_t)row * NROW;
  uint32_t* b = bits + (size_t)row * 192;
  const int t = threadIdx.x;
  #pragma unroll
  for (int it = 0; it < 6; ++it) {
    int idx = it * 1024 + t * 4;
    float4 x = *(const float4*)&a[idx];
    uint32_t nib = (x.x != 0.f ? 1u : 0u) | (x.y != 0.f ? 2u : 0u) |
                   (x.z != 0.f ? 4u : 0u) | (x.w != 0.f ? 8u : 0u);
    uint32_t m = nib << ((t & 7) * 4);
    m |= __shfl_xor(m, 1);
    m |= __shfl_xor(m, 2);
    m |= __shfl_xor(m, 4);
    if ((t & 7) == 0) b[idx >> 5] = m;
  }
}

// ---------------- one-shot weight conversion: 13 segments in a single launch
struct WConv {
  const float* src[13];
  _Float16* dst[13];
  int n4[13];
  float scale[13];
};
__global__ __launch_bounds__(256)
void convert_weights(WConv w)
{
  const int seg = blockIdx.x >> 4;
  const int bi = blockIdx.x & 15;
  const float* x = w.src[seg];
  _Float16* y = w.dst[seg];
  const float sc = w.scale[seg];
  const int n4 = w.n4[seg];
  for (int i = bi * 256 + threadIdx.x; i < n4; i += 16 * 256) {
    float4 v = ((const float4*)x)[i];
    half4v o;
    o[0] = (_Float16)(v.x * sc); o[1] = (_Float16)(v.y * sc);
    o[2] = (_Float16)(v.z * sc); o[3] = (_Float16)(v.w * sc);
    ((half4v*)y)[i] = o;
  }
}

// ---------------- dst[c][r] = f16(src[r][c] * rowscale[r]); src f32 [R,C], dst [C,R]
__global__ __launch_bounds__(256)
void transpose_scale_f16(const float* __restrict__ src, const float* __restrict__ rowscale,
                         _Float16* __restrict__ dst, int R, int C)
{
  __shared__ _Float16 tile[64][72];
  const int c0 = blockIdx.x * 64, r0 = blockIdx.y * 64;
  const int tx4 = (threadIdx.x & 15) * 4, ty = threadIdx.x >> 4;
  #pragma unroll
  for (int p = 0; p < 4; ++p) {
    int r = p * 16 + ty;
    float4 v = *(const float4*)&src[(size_t)(r0 + r) * C + c0 + tx4];
    float sc = rowscale ? rowscale[r0 + r] : 1.0f;
    tile[tx4 + 0][r] = (_Float16)(v.x * sc);
    tile[tx4 + 1][r] = (_Float16)(v.y * sc);
    tile[tx4 + 2][r] = (_Float16)(v.z * sc);
    tile[tx4 + 3][r] = (_Float16)(v.w * sc);
  }
  __syncthreads();
  #pragma unroll
  for (int p = 0; p < 4; ++p) {
    int c = p * 16 + ty;
    half4v o;
    o[0] = tile[c][tx4 + 0];
    o[1] = tile[c][tx4 + 1];
    o[2] = tile[c][tx4 + 2];
    o[3] = tile[c][tx4 + 3];
    *(half4v*)&dst[(size_t)(c0 + c) * R + r0 + tx4] = o;
  }
}

// ---------------- dst[c][r] = src[r*ld + c]; f16 -> f16 transpose
__global__ __launch_bounds__(256)
void transpose_f16(const _Float16* __restrict__ src, int ld,
                   _Float16* __restrict__ dst, int R, int C)
{
  __shared__ _Float16 tile[64][72];
  const int c0 = blockIdx.x * 64, r0 = blockIdx.y * 64;
  const int tx4 = (threadIdx.x & 15) * 4, ty = threadIdx.x >> 4;
  #pragma unroll
  for (int p = 0; p < 4; ++p) {
    int r = p * 16 + ty;
    half4v v = *(const half4v*)&src[(size_t)(r0 + r) * ld + c0 + tx4];
    tile[tx4 + 0][r] = v[0];
    tile[tx4 + 1][r] = v[1];
    tile[tx4 + 2][r] = v[2];
    tile[tx4 + 3][r] = v[3];
  }
  __syncthreads();
  #pragma unroll
  for (int p = 0; p < 4; ++p) {
    int c = p * 16 + ty;
    half4v o;
    o[0] = tile[c][tx4 + 0];
    o[1] = tile[c][tx4 + 1];
    o[2] = tile[c][tx4 + 2];
    o[3] = tile[c][tx4 + 3];
    *(half4v*)&dst[(size_t)(c0 + c) * R + r0 + tx4] = o;
  }
}

// ---------------- in-place masked softmax over f16 scores; writes UNNORMALIZED exp
// and linv[row] = 1/sum (normalization folded into PV reduce rowscale)
__global__ __launch_bounds__(256)
void softmax_mask16(_Float16* __restrict__ Sf, const uint32_t* __restrict__ bits,
                    float* __restrict__ linv)
{
  const int row = blockIdx.x;
  _Float16* s = Sf + (size_t)row * NROW;
  const uint32_t* b = bits + (size_t)row * 192;
  const int tid = threadIdx.x;
  float v[24];
  float m = NEG_INF;
  #pragma unroll
  for (int it = 0; it < 3; ++it) {
    int j = it * 2048 + tid * 8;
    half8 sv = *(const half8*)&s[j];
    uint32_t w = (b[j >> 5] >> (j & 31)) & 0xffu;
    #pragma unroll
    for (int e = 0; e < 8; ++e) {
      float x = ((w >> e) & 1u) ? (float)sv[e] : NEG_INF;
      v[it * 8 + e] = x;
      m = fmaxf(m, x);
    }
  }
  #pragma unroll
  for (int off = 32; off; off >>= 1) m = fmaxf(m, __shfl_xor(m, off));
  __shared__ float red[4];
  const int lane = tid & 63, wave = tid >> 6;
  if (lane == 0) red[wave] = m;
  __syncthreads();
  m = fmaxf(fmaxf(red[0], red[1]), fmaxf(red[2], red[3]));
  __syncthreads();
  float l = 0.f;
  #pragma unroll
  for (int k = 0; k < 24; ++k) {
    float e = (v[k] == NEG_INF) ? 0.f : __expf(v[k] - m);
    v[k] = e; l += e;
  }
  #pragma unroll
  for (int off = 32; off; off >>= 1) l += __shfl_xor(l, off);
  if (lane == 0) red[wave] = l;
  __syncthreads();
  l = red[0] + red[1] + red[2] + red[3];
  if (tid == 0) linv[row] = (l > 0.f) ? (1.f / l) : 0.f;
  #pragma unroll
  for (int it = 0; it < 3; ++it) {
    int j = it * 2048 + tid * 8;
    half8 o;
    #pragma unroll
    for (int e = 0; e < 8; ++e) o[e] = (_Float16)v[it * 8 + e];
    *(half8*)&s[j] = o;
  }
}

// ---------------- BN partial sums, vectorized half8, 64 rows per block
__global__ __launch_bounds__(256)
void bn_partial(const _Float16* __restrict__ X, int C,
                float* __restrict__ psum, float* __restrict__ psq)
{
  const int b = blockIdx.x;
  const int t = threadIdx.x;
  const int tpc = C >> 3;
  const int ng = 256 / tpc;
  const int g = t / tpc, c8 = (t % tpc) * 8;
  const int rpg = 64 / ng;
  const _Float16* x = X + (size_t)b * 64 * C;
  float s[8], q[8];
  #pragma unroll
  for (int e = 0; e < 8; ++e) { s[e] = 0.f; q[e] = 0.f; }
  for (int r = g * rpg; r < (g + 1) * rpg; ++r) {
    half8 v = *(const half8*)&x[(size_t)r * C + c8];
    #pragma unroll
    for (int e = 0; e < 8; ++e) {
      float f = (float)v[e];
      s[e] += f; q[e] += f * f;
    }
  }
  __shared__ float ls[256][8], lq[256][8];
  #pragma unroll
  for (int e = 0; e < 8; ++e) { ls[t][e] = s[e]; lq[t][e] = q[e]; }
  __syncthreads();
  for (int u = t; u < C; u += 256) {
    float ss = 0, qq = 0;
    for (int gg = 0; gg < ng; ++gg) {
      ss += ls[gg * tpc + (u >> 3)][u & 7];
      qq += lq[gg * tpc + (u >> 3)][u & 7];
    }
    psum[b * C + u] = ss; psq[b * C + u] = qq;
  }
}

__global__ void bn_finalize(const float* __restrict__ psum, const float* __restrict__ psq,
                            int C, int nb,
                            const float* __restrict__ g, const float* __restrict__ beta,
                            float* __restrict__ scale, float* __restrict__ shift)
{
  int c = threadIdx.x + blockIdx.x * blockDim.x;
  if (c >= C) return;
  float s = 0, q = 0;
  for (int b = 0; b < nb; ++b) { s += psum[(size_t)b * C + c]; q += psq[(size_t)b * C + c]; }
  const float invN = 1.0f / 6144.0f;
  float mean = s * invN;
  float var = q * invN - mean * mean;
  float rstd = rsqrtf(fmaxf(var, 0.f) + 1e-5f);
  float sc = g[c] * rstd;
  scale[c] = sc;
  shift[c] = beta[c] - mean * sc;
}

// ---------------- y = relu?(x*scale[c]+shift[c]) + residual(f16); half8-vectorized
__global__ __launch_bounds__(256)
void bn_apply(const _Float16* __restrict__ X, const float* __restrict__ scale,
              const float* __restrict__ shift, const _Float16* __restrict__ residual,
              float* __restrict__ Yf, _Float16* __restrict__ Yh,
              int Cmask, long total8, int do_relu)
{
  for (long i = (long)blockIdx.x * 256 + threadIdx.x; i < total8; i += (long)gridDim.x * 256) {
    long e0 = i * 8;
    int c0 = (int)(e0 & (long)Cmask);
    half8 xv = ((const half8*)X)[i];
    half8 rv;
    if (residual) rv = ((const half8*)residual)[i];
    float v[8];
    #pragma unroll
    for (int e = 0; e < 8; ++e) {
      float f = (float)xv[e] * scale[c0 + e] + shift[c0 + e];
      if (do_relu) f = fmaxf(f, 0.f);
      if (residual) f += (float)rv[e];
      v[e] = f;
    }
    if (Yf) {
      float4 o0, o1;
      o0.x = v[0]; o0.y = v[1]; o0.z = v[2]; o0.w = v[3];
      o1.x = v[4]; o1.y = v[5]; o1.z = v[6]; o1.w = v[7];
      ((float4*)Yf)[i * 2] = o0;
      ((float4*)Yf)[i * 2 + 1] = o1;
    }
    if (Yh) {
      half8 o;
      #pragma unroll
      for (int e = 0; e < 8; ++e) o[e] = (_Float16)v[e];
      ((half8*)Yh)[i] = o;
    }
  }
}

extern "C" void kernel_launch(void* const* d_in, const int* in_sizes, int n_in,
                              void* d_out, int out_size, void* d_ws, size_t ws_size,
                              hipStream_t stream)
{
  (void)in_sizes; (void)n_in; (void)out_size; (void)ws_size;
  const float* X     = (const float*)d_in[0];
  const float* adj   = (const float*)d_in[1];
  const float* adjg  = (const float*)d_in[2];
  const float* Wp    = (const float*)d_in[3];
  const float* gp    = (const float*)d_in[5];
  const float* betap = (const float*)d_in[6];

  float* out_h     = (float*)d_out;                       // [6144,256]
  float* out_embed = out_h + (size_t)NROW * DOUT;         // [6144,512]

  char* base = (char*)d_ws;
  size_t off = 0;
  auto alloc = [&](size_t bytes) -> void* {
    void* p = base + off;
    off += (bytes + 255) & ~(size_t)255;
    return p;
  };

  const long MN512 = (long)NROW * 512;

  _Float16* Ag  = (_Float16*)alloc((size_t)NROW * NROW * 2);   // adjg f16; reused as scores Sf
  _Float16* Sf  = Ag;
  uint32_t* bits = (uint32_t*)alloc((size_t)NROW * 192 * 4);
  _Float16* Pk  = (_Float16*)alloc((size_t)8 * MN512 * 2);     // split-K partials (f16)
  _Float16* XsT = (_Float16*)alloc((size_t)HDIM * NROW * 2);
  _Float16* Yh16 = (_Float16*)alloc((size_t)NROW * HDIM * 2);
  _Float16* Wph = (_Float16*)alloc((size_t)HDIM * HDIM * 2);
  _Float16* QKVW[3];
  for (int i = 0; i < 3; ++i) QKVW[i] = (_Float16*)alloc((size_t)1536 * HDIM * 2);
  _Float16* Woh[3];
  Woh[0] = (_Float16*)alloc((size_t)512 * 512 * 2);
  Woh[1] = (_Float16*)alloc((size_t)512 * 512 * 2);
  Woh[2] = (_Float16*)alloc((size_t)256 * 512 * 2);
  _Float16* QKVh = (_Float16*)alloc((size_t)NROW * 1536 * 2);
  _Float16* VTh  = (_Float16*)alloc((size_t)HDIM * NROW * 2);
  _Float16* AVh  = (_Float16*)alloc((size_t)NROW * HDIM * 2);
  _Float16* xh   = (_Float16*)alloc((size_t)NROW * HDIM * 2);
  _Float16* hb16A = (_Float16*)alloc((size_t)NROW * HDIM * 2);
  _Float16* hb16B = (_Float16*)alloc((size_t)NROW * HDIM * 2);
  float* dis  = (float*)alloc((size_t)NROW * 4);
  float* linv = (float*)alloc((size_t)NROW * 4);
  float* psum = (float*)alloc((size_t)96 * 512 * 4);
  float* psq  = (float*)alloc((size_t)96 * 512 * 4);
  float* bnsc = (float*)alloc(512 * 4);
  float* bnsh = (float*)alloc(512 * 4);

  const float qk_scale = 0.21022410381342863f;  // 512^(-1/4); folded into both Wq and Wk

  degree_convert<<<NROW, 256, 0, stream>>>(adjg, Ag, dis);
  build_mask<<<NROW, 256, 0, stream>>>(adj, bits);
  transpose_scale_f16<<<dim3(8, 96), 256, 0, stream>>>(X, dis, XsT, NROW, HDIM);

  {
    WConv w;
    int seg = 0;
    w.src[seg] = Wp; w.dst[seg] = Wph; w.n4[seg] = 512 * 512 / 4; w.scale[seg] = 1.f; ++seg;
    for (int i = 0; i < 3; ++i) {
      int o = (i < 2) ? 512 : 256;
      w.src[seg] = (const float*)d_in[7 + i * 7 + 0]; w.dst[seg] = QKVW[i];
      w.n4[seg] = 512 * 512 / 4; w.scale[seg] = qk_scale; ++seg;
      w.src[seg] = (const float*)d_in[7 + i * 7 + 1]; w.dst[seg] = QKVW[i] + 512 * 512;
      w.n4[seg] = 512 * 512 / 4; w.scale[seg] = qk_scale; ++seg;
      w.src[seg] = (const float*)d_in[7 + i * 7 + 2]; w.dst[seg] = QKVW[i] + 2 * 512 * 512;
      w.n4[seg] = 512 * 512 / 4; w.scale[seg] = 1.f; ++seg;
      w.src[seg] = (const float*)d_in[7 + i * 7 + 3]; w.dst[seg] = Woh[i];
      w.n4[seg] = o * 512 / 4; w.scale[seg] = 1.f; ++seg;
    }
    convert_weights<<<13 * 16, 256, 0, stream>>>(w);
  }

  // ---- embedding: h = BN( rowscale(dis) * (Ag @ XsT^T) @ Wp^T )   (bias cancels in BN)
  gemm256<<<dim3(24, 2, 8), 512, 0, stream>>>(Ag, NROW, XsT, NROW, Pk, 512, 768, MN512);
  reduce_splitk<<<1536, 256, 0, stream>>>(Pk, MN512, 8, 9, dis, nullptr, Yh16);
  gemm_f16<<<dim3(48, 4), 256, 0, stream>>>(Yh16, HDIM, Wph, HDIM, nullptr, xh, HDIM,
                                            512, nullptr, 0);
  bn_partial<<<96, 256, 0, stream>>>(xh, 512, psum, psq);
  bn_finalize<<<2, 256, 0, stream>>>(psum, psq, 512, 96, gp, betap, bnsc, bnsh);
  bn_apply<<<1536, 256, 0, stream>>>(xh, bnsc, bnsh, nullptr, out_embed, hb16A,
                                     511, MN512 / 8, 0);

  _Float16* hbuf[2] = {hb16A, hb16B};
  int cur = 0;
  for (int i = 0; i < 3; ++i) {
    int o = (i < 2) ? 512 : 256;
    const float* gl = (const float*)d_in[7 + i * 7 + 5];
    const float* bl = (const float*)d_in[7 + i * 7 + 6];
    _Float16* hin = hbuf[cur];

    // fused QKV projection: [6144,1536]
    gemm_f16<<<dim3(48, 12), 256, 0, stream>>>(hin, HDIM, QKVW[i], HDIM, nullptr, QKVh, 1536,
                                               512, nullptr, 0);
    transpose_f16<<<dim3(8, 96), 256, 0, stream>>>(QKVh + 1024, 1536, VTh, NROW, HDIM);
    // raw scores (f16), then in-place masked softmax (unnormalized exp + linv)
    gemm256<<<dim3(24, 24), 512, 0, stream>>>(QKVh, 1536, QKVh + 512, 1536, Sf, NROW, 512, 0);
    softmax_mask16<<<NROW, 256, 0, stream>>>(Sf, bits, linv);
    // attn @ V (split-K 8), normalization via rowscale=linv in reduce
    gemm256<<<dim3(24, 2, 8), 512, 0, stream>>>(Sf, NROW, VTh, NROW, Pk, 512, 768, MN512);
    reduce_splitk<<<1536, 256, 0, stream>>>(Pk, MN512, 8, 9, linv, nullptr, AVh);
    // @ Wo^T direct (no split-K; bias cancels in BN)
    gemm_f16<<<dim3(48, o / 128), 256, 0, stream>>>(AVh, HDIM, Woh[i], HDIM,
                                                    nullptr, xh, o, 512, nullptr, 0);
    bn_partial<<<96, 256, 0, stream>>>(xh, o, psum, psq);
    bn_finalize<<<2, 256, 0, stream>>>(psum, psq, o, 96, gl, bl, bnsc, bnsh);
    if (i < 2) {
      bn_apply<<<1536, 256, 0, stream>>>(xh, bnsc, bnsh, hin, nullptr, hbuf[cur ^ 1],
                                         o - 1, (long)NROW * o / 8, 1);
      cur ^= 1;
    } else {
      bn_apply<<<768, 256, 0, stream>>>(xh, bnsc, bnsh, nullptr, out_h, nullptr,
                                        o - 1, (long)NROW * o / 8, 1);
    }
  }
}